// Round 7
// baseline (311.717 us; speedup 1.0000x reference)
//
#include <hip/hip_runtime.h>
#include <hip/hip_cooperative_groups.h>

namespace cg = cooperative_groups;

// One-VALU ballots: __builtin_amdgcn_ballot_w64(cond) is a single v_cmp whose
// SGPR-pair result we combine with s_and_b64. HIP's __ballot may materialize
// the bool first (3 VALU) — guard and fall back.
#if defined(__has_builtin)
#  if __has_builtin(__builtin_amdgcn_ballot_w64)
#    define BALLOT64(x) __builtin_amdgcn_ballot_w64(x)
#  else
#    define BALLOT64(x) __ballot(x)
#  endif
#else
#  define BALLOT64(x) __ballot(x)
#endif

#define CH 2   // words per mask work-item (both always in one super-block)
#define NQ 8   // emit chunks per super-block == words per emit chunk (64/NQ)

// Single cooperative kernel, 3 phases separated by grid.sync():
//   P0: bounds[A][8] = xl,xh,yl,yh,h,cx,cy,0 ; sbtot[NSB*A] = 0.
//   P1 (mask): grid-stride over (group c, 2-word chunk). Lane = point.
//       Per anchor j: scalar-loaded bounds, 5 single-v_cmp ballots combined
//       in SALU, deposit anchor j's word into lane j (2 v_cndmask). Store
//       maskT[wd][a] (lane stride 8B -> 512B coalesced). Per-lane popcount
//       atomicAdd into sbtot[sb][a] (replaces the whole scan kernel).
//   P2 (emit): grid-stride over (c, sb, q). Lane = anchor. Coalesced sbtot
//       row -> cross-sb base + total; coalesced popc prefix of words
//       [sb*64, sb*64+q*8); per-lane ffs bit-walk of 8 words emits hits to
//       ordered slots < n. Distributed tail-clear ([count,n)) and counts
//       (item cid==0) folded in.
// Slot of point i = #(in-box points with index < i) == reference cumsum.

__global__ __launch_bounds__(256) void fused_kernel(
    const float* __restrict__ pts, const float* __restrict__ anc,
    unsigned long long* __restrict__ maskT, int* __restrict__ sbtot,
    float* __restrict__ bounds,
    float* __restrict__ out_pts, float* __restrict__ out_cnt,
    int N, int n, int W, int A, int NSB, int NCH)
{
    const int lane   = threadIdx.x & 63;
    const int nwaves = gridDim.x * 4;
    const int wv0    = blockIdx.x * 4 + (threadIdx.x >> 6);
    const int NGRP   = A >> 6;

    // ---- Phase 0: bounds + zero sbtot ----
    const int gt = blockIdx.x * 256 + threadIdx.x;
    if (gt < A) {
        const float cx = anc[gt * 6 + 0], cy = anc[gt * 6 + 1];
        const float w  = anc[gt * 6 + 3], l  = anc[gt * 6 + 4], h = anc[gt * 6 + 5];
        float* b = bounds + (size_t)gt * 8;
        b[0] = cx - 0.5f * w; b[1] = cx + 0.5f * w;
        b[2] = cy - 0.5f * l; b[3] = cy + 0.5f * l;
        b[4] = h; b[5] = cx; b[6] = cy; b[7] = 0.0f;
    }
    for (int i = gt; i < NSB * A; i += gridDim.x * 256) sbtot[i] = 0;

    cg::this_grid().sync();

    // ---- Phase 1: mask + popcount atomics ----
    for (int it0 = wv0; it0 < NGRP * NCH; it0 += nwaves) {
        const int it  = __builtin_amdgcn_readfirstlane(it0);
        const int c   = it / NCH;
        const int wd0 = (it % NCH) * CH;

        float px[CH], py[CH], pz[CH];
        unsigned long long zv[CH], myw[CH];
        #pragma unroll
        for (int u = 0; u < CH; ++u) {
            const int wd = wd0 + u;
            const int i  = wd * 64 + lane;
            const int ic = i < N ? i : N - 1;
            px[u] = pts[3 * ic + 0];
            py[u] = pts[3 * ic + 1];
            pz[u] = pts[3 * ic + 2];
            zv[u] = BALLOT64(pz[u] >= 0.0f) & BALLOT64(i < N);
            myw[u] = 0ull;
        }

        const float* bb = bounds + (size_t)c * 64 * 8;
        #pragma unroll 8
        for (int j = 0; j < 64; ++j) {
            const float xl = bb[j * 8 + 0], xh = bb[j * 8 + 1];  // uniform -> s_load
            const float yl = bb[j * 8 + 2], yh = bb[j * 8 + 3];
            const float hh = bb[j * 8 + 4];
            #pragma unroll
            for (int u = 0; u < CH; ++u) {
                const unsigned long long b =
                    BALLOT64(px[u] >= xl) & BALLOT64(px[u] <= xh) &
                    BALLOT64(py[u] >= yl) & BALLOT64(py[u] <= yh) &
                    BALLOT64(pz[u] <= hh) & zv[u];         // s_and_b64 combines
                if (lane == j) myw[u] = b;                 // 2 v_cndmask
            }
        }

        int pcs = 0;
        #pragma unroll
        for (int u = 0; u < CH; ++u) {
            pcs += __popcll(myw[u]);
            const int wd = wd0 + u;
            if (wd < W) maskT[(size_t)wd * A + (c * 64 + lane)] = myw[u];
        }
        atomicAdd(&sbtot[(wd0 >> 6) * A + (c * 64 + lane)], pcs);
    }

    cg::this_grid().sync();

    // ---- Phase 2: emit ----
    const int nch = NSB * NQ;
    const int ts  = (n + nch - 1) / nch;
    for (int it0 = wv0; it0 < NGRP * nch; it0 += nwaves) {
        const int it  = __builtin_amdgcn_readfirstlane(it0);
        const int c   = it / nch;
        const int cid = it % nch;
        const int sb  = cid / NQ, q = cid % NQ;
        const int a   = c * 64 + lane;

        int base = 0, total = 0;
        for (int k = 0; k < NSB; ++k) {          // coalesced sbtot rows
            const int v = sbtot[k * A + a];
            if (k < sb) base += v;
            total += v;
        }
        const int count = total < n ? total : n;
        if (cid == 0) out_cnt[a] = (float)count;

        float* const outa = out_pts + (size_t)a * n * 3;
        for (int s = cid * ts; s < cid * ts + ts; ++s) {   // distributed clear
            if (s >= count && s < n) {
                outa[3 * s + 0] = 0.f; outa[3 * s + 1] = 0.f; outa[3 * s + 2] = 0.f;
            }
        }

        const int wds = sb * 64;
        for (int k = 0; k < q * NQ; ++k) {       // coalesced popc prefix
            const int wd = wds + k;
            if (wd < W) base += __popcll(maskT[(size_t)wd * A + a]);
        }
        if (base >= n) continue;

        const float cx = bounds[a * 8 + 5], cy = bounds[a * 8 + 6];
        for (int k = 0; k < NQ; ++k) {
            const int wd = wds + q * NQ + k;
            if (wd >= W) break;
            unsigned long long w = maskT[(size_t)wd * A + a];   // coalesced
            while (w && base < n) {
                const int bix = __ffsll((long long)w) - 1;
                w &= w - 1ull;
                const int i = wd * 64 + bix;     // i < N (bit never set OOB)
                float* o = outa + (size_t)base * 3;
                o[0] = pts[3 * i + 0] - cx;
                o[1] = pts[3 * i + 1] - cy;
                o[2] = pts[3 * i + 2];
                ++base;
            }
            if (base >= n) break;
        }
    }
}

// ---- Fallback (round-1 kernel) used only if ws too small / A % 64 != 0 ----
__global__ __launch_bounds__(256) void roi_pool_kernel(
    const float* __restrict__ pts, const float* __restrict__ anc,
    float* __restrict__ out_pts, float* __restrict__ out_cnt, int N, int n)
{
    const int a = blockIdx.x;
    const float cx = anc[a * 6 + 0], cy = anc[a * 6 + 1];
    const float w  = anc[a * 6 + 3], l  = anc[a * 6 + 4], h = anc[a * 6 + 5];
    const float xmin = cx - 0.5f * w, xmax = cx + 0.5f * w;
    const float ymin = cy - 0.5f * l, ymax = cy + 0.5f * l;
    const int tid = threadIdx.x, wave = tid >> 6, lane = tid & 63;
    __shared__ int s_tot[4];
    int base = 0;
    float* const outa = out_pts + (size_t)a * n * 3;
    for (int start = 0; start < N; start += 256) {
        const int i = start + tid;
        bool m = false;
        float px = 0.f, py = 0.f, pz = 0.f;
        if (i < N) {
            px = pts[3 * i]; py = pts[3 * i + 1]; pz = pts[3 * i + 2];
            m = (px >= xmin) & (px <= xmax) & (py >= ymin) & (py <= ymax) &
                (pz >= 0.0f) & (pz <= h);
        }
        const unsigned long long ball = __ballot(m);
        const int lanePfx = __popcll(ball & ((1ull << lane) - 1ull));
        if (lane == 0) s_tot[wave] = __popcll(ball);
        __syncthreads();
        const int t0 = s_tot[0], t1 = s_tot[1], t2 = s_tot[2], t3 = s_tot[3];
        int offs = base;
        if (wave > 0) offs += t0;
        if (wave > 1) offs += t1;
        if (wave > 2) offs += t2;
        const int slot = offs + lanePfx;
        if (m && slot < n) {
            float* o = outa + (size_t)slot * 3;
            o[0] = px - cx; o[1] = py - cy; o[2] = pz;
        }
        base += t0 + t1 + t2 + t3;
        __syncthreads();
        if (base >= n) break;
    }
    const int count = base < n ? base : n;
    if (tid == 0) out_cnt[a] = (float)count;
    for (int s = count + tid; s < n; s += 256) {
        float* o = outa + (size_t)s * 3;
        o[0] = 0.f; o[1] = 0.f; o[2] = 0.f;
    }
}

extern "C" void kernel_launch(void* const* d_in, const int* in_sizes, int n_in,
                              void* d_out, int out_size, void* d_ws, size_t ws_size,
                              hipStream_t stream) {
    const float* pts = (const float*)d_in[0];
    const float* anc = (const float*)d_in[1];
    int N = in_sizes[0] / 3;          // 100000
    int A = in_sizes[1] / 6;          // 1024
    int n = (out_size / A - 1) / 3;   // 512

    float* out_pts = (float*)d_out;
    float* out_cnt = (float*)d_out + (size_t)A * n * 3;

    int W   = (N + 63) / 64;          // words per anchor (1563)
    int NSB = (W + 63) / 64;          // 64-word super-blocks (25)
    int NCH = (W + CH - 1) / CH;      // 2-word mask chunks (782)

    const size_t mask_bytes  = ((size_t)W * A + 64) * 8;
    const size_t sbtot_bytes = (size_t)NSB * A * sizeof(int);
    const size_t bound_bytes = (size_t)A * 8 * sizeof(float);

    if ((A & 63) || ws_size < mask_bytes + sbtot_bytes + bound_bytes) {
        roi_pool_kernel<<<dim3(A), dim3(256), 0, stream>>>(pts, anc, out_pts, out_cnt, N, n);
        return;
    }

    unsigned long long* maskT = (unsigned long long*)d_ws;
    int*   sbtot  = (int*)((char*)d_ws + mask_bytes);
    float* bounds = (float*)((char*)d_ws + mask_bytes + sbtot_bytes);

    // 1024 blocks x 256 thr = 4 blocks/CU (16 waves/CU), low VGPR -> safely
    // co-resident for the cooperative grid sync.
    void* args[] = {
        (void*)&pts, (void*)&anc, (void*)&maskT, (void*)&sbtot, (void*)&bounds,
        (void*)&out_pts, (void*)&out_cnt,
        (void*)&N, (void*)&n, (void*)&W, (void*)&A, (void*)&NSB, (void*)&NCH
    };
    hipLaunchCooperativeKernel((void*)fused_kernel, dim3(1024), dim3(256),
                               args, 0, stream);
}

// Round 8
// 122.095 us; speedup vs baseline: 2.5531x; 2.5531x over previous
//
#include <hip/hip_runtime.h>

// ROI point pooling, 3 stream-ordered kernels, latency-oriented.
//
// prep_clear: bounds[A][8] = xl,xh,yl,yh,h,cx,cy,0 ; float4-clears out_pts.
// mask:  wave = (anchor-group c of 64, 8-word block g). Lane = point.
//        24 up-front point loads; per anchor j: s_load bounds row, 5
//        single-v_cmp ballots (ballot_w64) combined with s_and_b64, deposit
//        anchor j's words into lane j. Stores maskT[wd][a] (512B coalesced)
//        and the per-block popcount qtot[g][a] (coalesced) -- no atomics,
//        no scan kernel.
// emit:  wave = (c, g), lane = anchor a. base = sum qtot[k<g][a] with 8-way
//        unrolled loads (8 independent loads per waitcnt -- the serial
//        load->wait->add chain was R6/R7's hidden stall). Walk the block's
//        <=8 words, ffs-emit in-box points to ordered slots < n. Block
//        g==last also writes counts[a] = min(total, n).
//
// Slot of point i = #(in-box points with index < i) == reference cumsum.

#if defined(__has_builtin)
#  if __has_builtin(__builtin_amdgcn_ballot_w64)
#    define BALLOT64(x) __builtin_amdgcn_ballot_w64(x)
#  else
#    define BALLOT64(x) __ballot(x)
#  endif
#else
#  define BALLOT64(x) __ballot(x)
#endif

#define BW 8   // words per block (512 points)

__global__ __launch_bounds__(256) void prep_clear_kernel(
    const float* __restrict__ anc, float* __restrict__ bounds,
    float* __restrict__ out_pts, int A, int clear4)
{
    const int gt = blockIdx.x * 256 + threadIdx.x;
    if (gt < A) {
        const float cx = anc[gt * 6 + 0], cy = anc[gt * 6 + 1];
        const float w  = anc[gt * 6 + 3], l  = anc[gt * 6 + 4], h = anc[gt * 6 + 5];
        float* b = bounds + (size_t)gt * 8;
        b[0] = cx - 0.5f * w; b[1] = cx + 0.5f * w;
        b[2] = cy - 0.5f * l; b[3] = cy + 0.5f * l;
        b[4] = h; b[5] = cx; b[6] = cy; b[7] = 0.0f;
    }
    for (int i = gt; i < clear4; i += gridDim.x * 256)
        ((float4*)out_pts)[i] = make_float4(0.f, 0.f, 0.f, 0.f);
}

__global__ __launch_bounds__(256) void mask_kernel(
    const float* __restrict__ pts, const float* __restrict__ bounds,
    unsigned long long* __restrict__ maskT, int* __restrict__ qtot,
    int N, int W, int A, int NQB)
{
    const int it = __builtin_amdgcn_readfirstlane(blockIdx.x * 4 + (threadIdx.x >> 6));
    const int lane = threadIdx.x & 63;
    const int NGRP = A >> 6;
    if (it >= NGRP * NQB) return;
    const int c   = it / NQB;          // anchor group (uniform)
    const int g   = it % NQB;          // 8-word block (uniform)
    const int wd0 = g * BW;

    float px[BW], py[BW], pz[BW];
    unsigned long long zv[BW], myw[BW];
    #pragma unroll
    for (int u = 0; u < BW; ++u) {
        const int i  = (wd0 + u) * 64 + lane;
        const int ic = i < N ? i : N - 1;
        px[u] = pts[3 * ic + 0];
        py[u] = pts[3 * ic + 1];
        pz[u] = pts[3 * ic + 2];
        zv[u] = BALLOT64(pz[u] >= 0.0f) & BALLOT64(i < N);
        myw[u] = 0ull;
    }

    const float* bb = bounds + (size_t)c * 64 * 8;
    #pragma unroll 4
    for (int j = 0; j < 64; ++j) {
        const float xl = bb[j * 8 + 0], xh = bb[j * 8 + 1];  // uniform -> s_load
        const float yl = bb[j * 8 + 2], yh = bb[j * 8 + 3];
        const float hh = bb[j * 8 + 4];
        #pragma unroll
        for (int u = 0; u < BW; ++u) {
            const unsigned long long b =
                BALLOT64(px[u] >= xl) & BALLOT64(px[u] <= xh) &
                BALLOT64(py[u] >= yl) & BALLOT64(py[u] <= yh) &
                BALLOT64(pz[u] <= hh) & zv[u];        // s_and_b64 combines
            if (lane == j) myw[u] = b;                // 2 v_cndmask / writelane
        }
    }

    const int a = c * 64 + lane;
    int pcs = 0;
    #pragma unroll
    for (int u = 0; u < BW; ++u) {
        pcs += __popcll(myw[u]);                      // wd>=W words are all-0
        const int wd = wd0 + u;
        if (wd < W) maskT[(size_t)wd * A + a] = myw[u];  // 512B coalesced
    }
    qtot[g * A + a] = pcs;                            // coalesced, no atomics
}

__global__ __launch_bounds__(256) void emit_kernel(
    const float* __restrict__ pts, const float* __restrict__ bounds,
    const unsigned long long* __restrict__ maskT, const int* __restrict__ qtot,
    float* __restrict__ out_pts, float* __restrict__ out_cnt,
    int n, int A, int W, int NQB)
{
    const int it = __builtin_amdgcn_readfirstlane(blockIdx.x * 4 + (threadIdx.x >> 6));
    const int lane = threadIdx.x & 63;
    const int NGRP = A >> 6;
    if (it >= NGRP * NQB) return;
    const int c = it / NQB;
    const int g = it % NQB;
    const int a = c * 64 + lane;
    const int wd0 = g * BW;

    // Exclusive prefix over qtot rows, 8-way unrolled: 8 independent
    // coalesced loads per waitcnt instead of a serial load->wait->add chain.
    int base = 0;
    {
        int k = 0;
        for (; k + 8 <= g; k += 8) {
            const int v0 = qtot[(k + 0) * A + a], v1 = qtot[(k + 1) * A + a];
            const int v2 = qtot[(k + 2) * A + a], v3 = qtot[(k + 3) * A + a];
            const int v4 = qtot[(k + 4) * A + a], v5 = qtot[(k + 5) * A + a];
            const int v6 = qtot[(k + 6) * A + a], v7 = qtot[(k + 7) * A + a];
            base += ((v0 + v1) + (v2 + v3)) + ((v4 + v5) + (v6 + v7));
        }
        for (; k < g; ++k) base += qtot[k * A + a];
    }

    if (g == NQB - 1) {                 // last block also writes counts
        int own = 0;
        #pragma unroll
        for (int u = 0; u < BW; ++u) {
            const int wd = wd0 + u;
            if (wd < W) own += __popcll(maskT[(size_t)wd * A + a]);
        }
        const int total = base + own;
        out_cnt[a] = (float)(total < n ? total : n);
    }

    if (base >= n) return;              // per-lane: all slots past the clamp

    const float cx = bounds[a * 8 + 5], cy = bounds[a * 8 + 6];
    float* const outa = out_pts + (size_t)a * n * 3;
    #pragma unroll
    for (int u = 0; u < BW; ++u) {
        const int wd = wd0 + u;
        if (wd >= W) break;
        unsigned long long w = maskT[(size_t)wd * A + a];   // coalesced
        while (w && base < n) {
            const int bix = __ffsll((long long)w) - 1;
            w &= w - 1ull;
            const int i = wd * 64 + bix;          // bit never set for i >= N
            float* o = outa + (size_t)base * 3;
            o[0] = pts[3 * i + 0] - cx;
            o[1] = pts[3 * i + 1] - cy;
            o[2] = pts[3 * i + 2];
            ++base;
        }
        if (base >= n) break;
    }
}

// ---- Fallback (round-1 kernel) used only if A % 64 != 0 / ws too small ----
__global__ __launch_bounds__(256) void roi_pool_kernel(
    const float* __restrict__ pts, const float* __restrict__ anc,
    float* __restrict__ out_pts, float* __restrict__ out_cnt, int N, int n)
{
    const int a = blockIdx.x;
    const float cx = anc[a * 6 + 0], cy = anc[a * 6 + 1];
    const float w  = anc[a * 6 + 3], l  = anc[a * 6 + 4], h = anc[a * 6 + 5];
    const float xmin = cx - 0.5f * w, xmax = cx + 0.5f * w;
    const float ymin = cy - 0.5f * l, ymax = cy + 0.5f * l;
    const int tid = threadIdx.x, wave = tid >> 6, lane = tid & 63;
    __shared__ int s_tot[4];
    int base = 0;
    float* const outa = out_pts + (size_t)a * n * 3;
    for (int start = 0; start < N; start += 256) {
        const int i = start + tid;
        bool m = false;
        float px = 0.f, py = 0.f, pz = 0.f;
        if (i < N) {
            px = pts[3 * i]; py = pts[3 * i + 1]; pz = pts[3 * i + 2];
            m = (px >= xmin) & (px <= xmax) & (py >= ymin) & (py <= ymax) &
                (pz >= 0.0f) & (pz <= h);
        }
        const unsigned long long ball = __ballot(m);
        const int lanePfx = __popcll(ball & ((1ull << lane) - 1ull));
        if (lane == 0) s_tot[wave] = __popcll(ball);
        __syncthreads();
        const int t0 = s_tot[0], t1 = s_tot[1], t2 = s_tot[2], t3 = s_tot[3];
        int offs = base;
        if (wave > 0) offs += t0;
        if (wave > 1) offs += t1;
        if (wave > 2) offs += t2;
        const int slot = offs + lanePfx;
        if (m && slot < n) {
            float* o = outa + (size_t)slot * 3;
            o[0] = px - cx; o[1] = py - cy; o[2] = pz;
        }
        base += t0 + t1 + t2 + t3;
        __syncthreads();
        if (base >= n) break;
    }
    const int count = base < n ? base : n;
    if (tid == 0) out_cnt[a] = (float)count;
    for (int s = count + tid; s < n; s += 256) {
        float* o = outa + (size_t)s * 3;
        o[0] = 0.f; o[1] = 0.f; o[2] = 0.f;
    }
}

extern "C" void kernel_launch(void* const* d_in, const int* in_sizes, int n_in,
                              void* d_out, int out_size, void* d_ws, size_t ws_size,
                              hipStream_t stream) {
    const float* pts = (const float*)d_in[0];
    const float* anc = (const float*)d_in[1];
    const int N = in_sizes[0] / 3;          // 100000
    const int A = in_sizes[1] / 6;          // 1024
    const int n = (out_size / A - 1) / 3;   // 512

    float* out_pts = (float*)d_out;
    float* out_cnt = (float*)d_out + (size_t)A * n * 3;

    const int W   = (N + 63) / 64;          // words per anchor (1563)
    const int NQB = (W + BW - 1) / BW;      // 8-word blocks (196)

    const size_t mask_bytes  = (size_t)W * A * 8;
    const size_t qtot_bytes  = (size_t)NQB * A * sizeof(int);
    const size_t bound_bytes = (size_t)A * 8 * sizeof(float);

    if ((A & 63) || ws_size < mask_bytes + qtot_bytes + bound_bytes) {
        roi_pool_kernel<<<dim3(A), dim3(256), 0, stream>>>(pts, anc, out_pts, out_cnt, N, n);
        return;
    }

    unsigned long long* maskT = (unsigned long long*)d_ws;
    int*   qtot   = (int*)((char*)d_ws + mask_bytes);
    float* bounds = (float*)((char*)d_ws + mask_bytes + qtot_bytes);

    const int NGRP   = A >> 6;
    const int waves  = NGRP * NQB;          // 3136
    const int blocks = (waves + 3) / 4;     // 784
    const int clear4 = (A * n * 3) / 4;     // 393216 float4s

    prep_clear_kernel<<<dim3(1536), dim3(256), 0, stream>>>(anc, bounds, out_pts, A, clear4);
    mask_kernel<<<dim3(blocks), dim3(256), 0, stream>>>(pts, bounds, maskT, qtot, N, W, A, NQB);
    emit_kernel<<<dim3(blocks), dim3(256), 0, stream>>>(pts, bounds, maskT, qtot,
                                                        out_pts, out_cnt, n, A, W, NQB);
}

// Round 9
// 110.166 us; speedup vs baseline: 2.8295x; 1.1083x over previous
//
#include <hip/hip_runtime.h>

// ROI point pooling, 4 stream-ordered kernels.
//
// prep: bounds[A][8] = xl,xh,yl,yh,h,cx,cy,0 ; zeros sbtot.
// mask (BW=4 words/wave, 6256 waves): lane = point. Per anchor j: s_load
//   bounds row, 5 single-v_cmp ballots combined with s_and_b64, deposit
//   anchor j's words into lane j. Stores maskT[wd][a] (coalesced), qtot[g][a]
//   (per-block popcount), and atomicAdd into sbtot[g/16][a] (hierarchical
//   prefix input).
// E1 (index compaction): wave = (c,g), lane = anchor. base = sum sbtot[k<sb]
//   (<=24 rows) + sum qtot[sb*16..g) (<=15 rows), all coalesced + unrolled.
//   Walk own 4 words, ffs-emit 4B point-INDICES to idx[a][slot<n] (no point
//   loads / 12B stores in the serial chain). Last block writes counts.
// E2 (gather): wave = (a, 64-slot chunk), 8192 waves. Coalesced idx load,
//   divergent pts gather with ALL lanes active, coalesced 768B row stores;
//   slots >= count get zeros (absorbs the output clear; d_out is poisoned).
//
// Slot of point i = #(in-box points with index < i) == reference cumsum.

#if defined(__has_builtin)
#  if __has_builtin(__builtin_amdgcn_ballot_w64)
#    define BALLOT64(x) __builtin_amdgcn_ballot_w64(x)
#  else
#    define BALLOT64(x) __ballot(x)
#  endif
#else
#  define BALLOT64(x) __ballot(x)
#endif

#define BW  4    // words per mask/E1 block (256 points)
#define SBW 16   // qtot rows per sbtot row (4096 points)

__global__ __launch_bounds__(256) void prep_kernel(
    const float* __restrict__ anc, float* __restrict__ bounds,
    int* __restrict__ sbtot, int A, int nsb2)
{
    for (int gt = blockIdx.x * 256 + threadIdx.x; gt < A + nsb2 * A;
         gt += gridDim.x * 256) {
        if (gt < A) {
            const float cx = anc[gt * 6 + 0], cy = anc[gt * 6 + 1];
            const float w  = anc[gt * 6 + 3], l  = anc[gt * 6 + 4], h = anc[gt * 6 + 5];
            float* b = bounds + (size_t)gt * 8;
            b[0] = cx - 0.5f * w; b[1] = cx + 0.5f * w;
            b[2] = cy - 0.5f * l; b[3] = cy + 0.5f * l;
            b[4] = h; b[5] = cx; b[6] = cy; b[7] = 0.0f;
        } else {
            sbtot[gt - A] = 0;
        }
    }
}

__global__ __launch_bounds__(256) void mask_kernel(
    const float* __restrict__ pts, const float* __restrict__ bounds,
    unsigned long long* __restrict__ maskT, int* __restrict__ qtot,
    int* __restrict__ sbtot, int N, int W, int A, int NQB)
{
    const int it = __builtin_amdgcn_readfirstlane(blockIdx.x * 4 + (threadIdx.x >> 6));
    const int lane = threadIdx.x & 63;
    const int NGRP = A >> 6;
    if (it >= NGRP * NQB) return;
    const int c   = it / NQB;          // anchor group (uniform)
    const int g   = it % NQB;          // 4-word block (uniform)
    const int wd0 = g * BW;

    float px[BW], py[BW], pz[BW];
    unsigned long long zv[BW], myw[BW];
    #pragma unroll
    for (int u = 0; u < BW; ++u) {
        const int i  = (wd0 + u) * 64 + lane;
        const int ic = i < N ? i : N - 1;
        px[u] = pts[3 * ic + 0];
        py[u] = pts[3 * ic + 1];
        pz[u] = pts[3 * ic + 2];
        zv[u] = BALLOT64(pz[u] >= 0.0f) & BALLOT64(i < N);
        myw[u] = 0ull;
    }

    const float* bb = bounds + (size_t)c * 64 * 8;
    #pragma unroll 8
    for (int j = 0; j < 64; ++j) {
        const float xl = bb[j * 8 + 0], xh = bb[j * 8 + 1];  // uniform -> s_load
        const float yl = bb[j * 8 + 2], yh = bb[j * 8 + 3];
        const float hh = bb[j * 8 + 4];
        #pragma unroll
        for (int u = 0; u < BW; ++u) {
            const unsigned long long b =
                BALLOT64(px[u] >= xl) & BALLOT64(px[u] <= xh) &
                BALLOT64(py[u] >= yl) & BALLOT64(py[u] <= yh) &
                BALLOT64(pz[u] <= hh) & zv[u];        // s_and_b64 combines
            if (lane == j) myw[u] = b;                // 2 v_cndmask
        }
    }

    const int a = c * 64 + lane;
    int pcs = 0;
    #pragma unroll
    for (int u = 0; u < BW; ++u) {
        pcs += __popcll(myw[u]);                      // OOB words are all-0
        const int wd = wd0 + u;
        if (wd < W) maskT[(size_t)wd * A + a] = myw[u];  // 512B coalesced
    }
    qtot[g * A + a] = pcs;                            // coalesced
    atomicAdd(&sbtot[(g / SBW) * A + a], pcs);        // hierarchical subtotal
}

__global__ __launch_bounds__(256) void e1_kernel(
    const unsigned long long* __restrict__ maskT, const int* __restrict__ qtot,
    const int* __restrict__ sbtot, int* __restrict__ idx,
    int* __restrict__ cnts, float* __restrict__ out_cnt,
    int n, int A, int W, int NQB)
{
    const int it = __builtin_amdgcn_readfirstlane(blockIdx.x * 4 + (threadIdx.x >> 6));
    const int lane = threadIdx.x & 63;
    const int NGRP = A >> 6;
    if (it >= NGRP * NQB) return;
    const int c  = it / NQB;
    const int g  = it % NQB;
    const int sb = g / SBW;
    const int a  = c * 64 + lane;

    // Hierarchical exclusive prefix: sbtot rows (8-way) + intra-sb qtot (4-way).
    int base = 0;
    {
        int k = 0;
        for (; k + 8 <= sb; k += 8) {
            const int v0 = sbtot[(k + 0) * A + a], v1 = sbtot[(k + 1) * A + a];
            const int v2 = sbtot[(k + 2) * A + a], v3 = sbtot[(k + 3) * A + a];
            const int v4 = sbtot[(k + 4) * A + a], v5 = sbtot[(k + 5) * A + a];
            const int v6 = sbtot[(k + 6) * A + a], v7 = sbtot[(k + 7) * A + a];
            base += ((v0 + v1) + (v2 + v3)) + ((v4 + v5) + (v6 + v7));
        }
        for (; k < sb; ++k) base += sbtot[k * A + a];
        int q = sb * SBW;
        for (; q + 4 <= g; q += 4) {
            const int v0 = qtot[(q + 0) * A + a], v1 = qtot[(q + 1) * A + a];
            const int v2 = qtot[(q + 2) * A + a], v3 = qtot[(q + 3) * A + a];
            base += (v0 + v1) + (v2 + v3);
        }
        for (; q < g; ++q) base += qtot[q * A + a];
    }

    // Walk own words; emit 4B indices (ordered); pos past n just counts.
    int pos = base;
    int* const idxa = idx + (size_t)a * n;
    #pragma unroll
    for (int u = 0; u < BW; ++u) {
        const int wd = g * BW + u;
        if (wd >= W) break;
        unsigned long long w = maskT[(size_t)wd * A + a];   // coalesced
        while (w) {
            const int bix = __ffsll((long long)w) - 1;
            w &= w - 1ull;
            if (pos < n) idxa[pos] = wd * 64 + bix;
            ++pos;
        }
    }

    if (g == NQB - 1) {                 // pos == total unclamped count
        const int cc = pos < n ? pos : n;
        cnts[a] = cc;
        out_cnt[a] = (float)cc;
    }
}

__global__ __launch_bounds__(256) void e2_kernel(
    const float* __restrict__ pts, const float* __restrict__ bounds,
    const int* __restrict__ idx, const int* __restrict__ cnts,
    float* __restrict__ out_pts, int n, int A, int KCH)
{
    const int wv = __builtin_amdgcn_readfirstlane(blockIdx.x * 4 + (threadIdx.x >> 6));
    const int lane = threadIdx.x & 63;
    if (wv >= A * KCH) return;
    const int a = wv / KCH;             // uniform -> s_loads below
    const int k = wv % KCH;

    const int cnt  = cnts[a];           // uniform
    const float cx = bounds[a * 8 + 5], cy = bounds[a * 8 + 6];
    const int slot = k * 64 + lane;
    if (slot >= n) return;

    float vx = 0.f, vy = 0.f, vz = 0.f;
    if (slot < cnt) {
        const int i = idx[(size_t)a * n + slot];   // coalesced 256B
        vx = pts[3 * i + 0] - cx;                  // divergent gather, all lanes
        vy = pts[3 * i + 1] - cy;
        vz = pts[3 * i + 2];
    }
    float* o = out_pts + ((size_t)a * n + slot) * 3;  // 768B/row coalesced
    o[0] = vx; o[1] = vy; o[2] = vz;
}

// ---- Fallback (round-1 kernel) used only if A % 64 != 0 / ws too small ----
__global__ __launch_bounds__(256) void roi_pool_kernel(
    const float* __restrict__ pts, const float* __restrict__ anc,
    float* __restrict__ out_pts, float* __restrict__ out_cnt, int N, int n)
{
    const int a = blockIdx.x;
    const float cx = anc[a * 6 + 0], cy = anc[a * 6 + 1];
    const float w  = anc[a * 6 + 3], l  = anc[a * 6 + 4], h = anc[a * 6 + 5];
    const float xmin = cx - 0.5f * w, xmax = cx + 0.5f * w;
    const float ymin = cy - 0.5f * l, ymax = cy + 0.5f * l;
    const int tid = threadIdx.x, wave = tid >> 6, lane = tid & 63;
    __shared__ int s_tot[4];
    int base = 0;
    float* const outa = out_pts + (size_t)a * n * 3;
    for (int start = 0; start < N; start += 256) {
        const int i = start + tid;
        bool m = false;
        float px = 0.f, py = 0.f, pz = 0.f;
        if (i < N) {
            px = pts[3 * i]; py = pts[3 * i + 1]; pz = pts[3 * i + 2];
            m = (px >= xmin) & (px <= xmax) & (py >= ymin) & (py <= ymax) &
                (pz >= 0.0f) & (pz <= h);
        }
        const unsigned long long ball = __ballot(m);
        const int lanePfx = __popcll(ball & ((1ull << lane) - 1ull));
        if (lane == 0) s_tot[wave] = __popcll(ball);
        __syncthreads();
        const int t0 = s_tot[0], t1 = s_tot[1], t2 = s_tot[2], t3 = s_tot[3];
        int offs = base;
        if (wave > 0) offs += t0;
        if (wave > 1) offs += t1;
        if (wave > 2) offs += t2;
        const int slot = offs + lanePfx;
        if (m && slot < n) {
            float* o = outa + (size_t)slot * 3;
            o[0] = px - cx; o[1] = py - cy; o[2] = pz;
        }
        base += t0 + t1 + t2 + t3;
        __syncthreads();
        if (base >= n) break;
    }
    const int count = base < n ? base : n;
    if (tid == 0) out_cnt[a] = (float)count;
    for (int s = count + tid; s < n; s += 256) {
        float* o = outa + (size_t)s * 3;
        o[0] = 0.f; o[1] = 0.f; o[2] = 0.f;
    }
}

extern "C" void kernel_launch(void* const* d_in, const int* in_sizes, int n_in,
                              void* d_out, int out_size, void* d_ws, size_t ws_size,
                              hipStream_t stream) {
    const float* pts = (const float*)d_in[0];
    const float* anc = (const float*)d_in[1];
    const int N = in_sizes[0] / 3;          // 100000
    const int A = in_sizes[1] / 6;          // 1024
    const int n = (out_size / A - 1) / 3;   // 512

    float* out_pts = (float*)d_out;
    float* out_cnt = (float*)d_out + (size_t)A * n * 3;

    const int W    = (N + 63) / 64;         // words per anchor (1563)
    const int NQB  = (W + BW - 1) / BW;     // 4-word blocks (391)
    const int NSB2 = (NQB + SBW - 1) / SBW; // sbtot rows (25)

    const size_t mask_bytes  = ((size_t)W * A + 64) * 8;
    const size_t qtot_bytes  = (size_t)NQB * A * sizeof(int);
    const size_t sbtot_bytes = (size_t)NSB2 * A * sizeof(int);
    const size_t bound_bytes = (size_t)A * 8 * sizeof(float);
    const size_t cnts_bytes  = (size_t)A * sizeof(int);
    const size_t idx_bytes   = (size_t)A * n * sizeof(int);
    const size_t total_ws = mask_bytes + qtot_bytes + sbtot_bytes +
                            bound_bytes + cnts_bytes + idx_bytes;

    if ((A & 63) || ws_size < total_ws) {
        roi_pool_kernel<<<dim3(A), dim3(256), 0, stream>>>(pts, anc, out_pts, out_cnt, N, n);
        return;
    }

    char* p = (char*)d_ws;
    unsigned long long* maskT = (unsigned long long*)p;  p += mask_bytes;
    int*   qtot   = (int*)p;    p += qtot_bytes;
    int*   sbtot  = (int*)p;    p += sbtot_bytes;
    float* bounds = (float*)p;  p += bound_bytes;
    int*   cnts   = (int*)p;    p += cnts_bytes;
    int*   idx    = (int*)p;

    const int NGRP   = A >> 6;
    const int mwaves = NGRP * NQB;          // 6256
    const int KCH    = (n + 63) / 64;       // 8 slot-chunks per anchor
    const int ewaves = A * KCH;             // 8192

    prep_kernel<<<dim3(104), dim3(256), 0, stream>>>(anc, bounds, sbtot, A, NSB2);
    mask_kernel<<<dim3((mwaves + 3) / 4), dim3(256), 0, stream>>>(
        pts, bounds, maskT, qtot, sbtot, N, W, A, NQB);
    e1_kernel<<<dim3((mwaves + 3) / 4), dim3(256), 0, stream>>>(
        maskT, qtot, sbtot, idx, cnts, out_cnt, n, A, W, NQB);
    e2_kernel<<<dim3((ewaves + 3) / 4), dim3(256), 0, stream>>>(
        pts, bounds, idx, cnts, out_pts, n, A, KCH);
}